// Round 2
// baseline (1538.415 us; speedup 1.0000x reference)
//
#include <hip/hip_runtime.h>
#include <math.h>

// Problem constants
#define N_POS     131072          // 8 * 16*32*32 positions
#define DIM       256
#define K_CODES   512
#define S_SPATIAL 16384           // 16*32*32
#define ZQ_ELEMS  33554432        // 8*256*16384
#define OUT_LOSS  33554432
#define OUT_IDXB  33554433        // idx written as float here
#define OUT_PERP  (33554433 + 131072)

// Workspace layout (bytes)
#define WS_LOSS   0               // double
#define WS_HIST   16              // int[512]
#define WS_E2     2064            // float[512]
#define WS_FIXED  2064            // bytes zeroed (loss + hist)

// ---------------------------------------------------------------------------
// numpy pairwise_sum replica for 256 contiguous squared elements, given a
// loader functor-ish via macro: we just write it twice (strided / contiguous).
//
// numpy: n=256 -> pairwise(128) + pairwise(128); each 128-block:
//   r[j] = a[j] (j=0..7); for i=8..120 step 8: r[j] += a[i+j];
//   res = ((r0+r1)+(r2+r3)) + ((r4+r5)+(r6+r7))
// All adds/muls fp32, square rounded before add (no FMA contraction).

// Kernel 1: codebook squared norms s_e[k], numpy-pairwise replica.
// One thread per code.
__global__ __launch_bounds__(256) void e2_kernel(const float* __restrict__ e,
                                                 float* __restrict__ e2) {
    int k = blockIdx.x * 256 + threadIdx.x;
    if (k >= K_CODES) return;
    const float* row = e + (size_t)k * DIM;
    float half[2];
#pragma unroll
    for (int h = 0; h < 2; ++h) {
        const float* base = row + h * 128;
        float r[8];
#pragma unroll
        for (int j = 0; j < 8; ++j) {
            float v = base[j];
            r[j] = __fmul_rn(v, v);
        }
        for (int i = 8; i < 128; i += 8) {
#pragma unroll
            for (int j = 0; j < 8; ++j) {
                float v = base[i + j];
                r[j] = __fadd_rn(r[j], __fmul_rn(v, v));
            }
        }
        half[h] = __fadd_rn(__fadd_rn(__fadd_rn(r[0], r[1]), __fadd_rn(r[2], r[3])),
                            __fadd_rn(__fadd_rn(r[4], r[5]), __fadd_rn(r[6], r[7])));
    }
    e2[k] = __fadd_rn(half[0], half[1]);
}

// ---------------------------------------------------------------------------
// Kernel 2: fp32 distance + argmin, bit-replicating numpy:
//   d[n,k] = fl( fl(s_z[n] + s_e[k]) - fl(2 * G[n,k]) )
//   G[n,k] = sequential fp32 FMA over d=0..255 (BLAS microkernel order)
//   argmin: first index on ties (strict <).
__global__ __launch_bounds__(256) void pass1_dist(const float* __restrict__ z,
                                                  const float* __restrict__ e,
                                                  const float* __restrict__ e2,
                                                  float* __restrict__ idxf) {
    int n = blockIdx.x * 256 + threadIdx.x;          // grid sized exactly
    int b = n >> 14;
    int s = n & (S_SPATIAL - 1);
    const float* zp = z + (size_t)b * (DIM * S_SPATIAL) + s;

    // s_z: numpy pairwise over fl(z_d^2), d = 0..255 (strided by S_SPATIAL)
    float sz;
    {
        float half[2];
#pragma unroll
        for (int h = 0; h < 2; ++h) {
            const float* base = zp + (size_t)(h * 128) * S_SPATIAL;
            float r[8];
#pragma unroll
            for (int j = 0; j < 8; ++j) {
                float v = base[(size_t)j * S_SPATIAL];
                r[j] = __fmul_rn(v, v);
            }
            for (int i = 8; i < 128; i += 8) {
#pragma unroll
                for (int j = 0; j < 8; ++j) {
                    float v = base[(size_t)(i + j) * S_SPATIAL];
                    r[j] = __fadd_rn(r[j], __fmul_rn(v, v));
                }
            }
            half[h] = __fadd_rn(__fadd_rn(__fadd_rn(r[0], r[1]), __fadd_rn(r[2], r[3])),
                                __fadd_rn(__fadd_rn(r[4], r[5]), __fadd_rn(r[6], r[7])));
        }
        sz = __fadd_rn(half[0], half[1]);
    }

    float best = 3.4e38f;
    int bidx = 0;

    for (int kt = 0; kt < K_CODES; kt += 32) {
        float acc[32];
#pragma unroll
        for (int k = 0; k < 32; ++k) acc[k] = 0.f;
        const float* eb = e + (size_t)kt * DIM;

        for (int d0 = 0; d0 < DIM; d0 += 4) {
            float z0 = zp[(size_t)(d0 + 0) * S_SPATIAL];
            float z1 = zp[(size_t)(d0 + 1) * S_SPATIAL];
            float z2 = zp[(size_t)(d0 + 2) * S_SPATIAL];
            float z3 = zp[(size_t)(d0 + 3) * S_SPATIAL];
#pragma unroll
            for (int k = 0; k < 32; ++k) {
                const float* ek = eb + k * DIM + d0;
                float a = acc[k];
                a = __fmaf_rn(z0, ek[0], a);   // sequential FMA, ascending d
                a = __fmaf_rn(z1, ek[1], a);
                a = __fmaf_rn(z2, ek[2], a);
                a = __fmaf_rn(z3, ek[3], a);
                acc[k] = a;
            }
        }
#pragma unroll
        for (int k = 0; k < 32; ++k) {
            float t1   = __fadd_rn(sz, e2[kt + k]);
            float dist = __fsub_rn(t1, __fmul_rn(2.0f, acc[k]));
            if (dist < best) { best = dist; bidx = kt + k; }   // first-index ties
        }
    }

    idxf[n] = (float)bidx;
}

// ---------------------------------------------------------------------------
// Kernel 3: gather z_q = fl(z + fl(e[idx] - z)) (straight-through replica)
// + accumulate sum(fl(e-z)^2) in double for the loss.
__global__ __launch_bounds__(256) void gather_loss(const float* __restrict__ z,
                                                   const float* __restrict__ e,
                                                   const float* __restrict__ idxf,
                                                   float* __restrict__ out,
                                                   double* __restrict__ loss) {
    size_t stride = (size_t)gridDim.x * blockDim.x;
    double s = 0.0;
    for (size_t i = (size_t)blockIdx.x * blockDim.x + threadIdx.x; i < ZQ_ELEMS; i += stride) {
        int b  = (int)(i >> 22);          // / (256*16384)
        int r  = (int)(i & 4194303);
        int d  = r >> 14;
        int sp = r & (S_SPATIAL - 1);
        int n  = (b << 14) + sp;
        int k  = (int)idxf[n];
        float ev = e[(size_t)k * DIM + d];
        float zv = z[i];
        float df = __fsub_rn(ev, zv);       // z_q_raw - z in fp32
        out[i] = __fadd_rn(zv, df);         // straight-through z_q
        s += (double)df * (double)df;
    }
    // block reduce (4 waves)
    for (int off = 32; off; off >>= 1) s += __shfl_down(s, off);
    __shared__ double red[4];
    if ((threadIdx.x & 63) == 0) red[threadIdx.x >> 6] = s;
    __syncthreads();
    if (threadIdx.x == 0) {
        double t = red[0] + red[1] + red[2] + red[3];
        atomicAdd(loss, t);
    }
}

// ---------------------------------------------------------------------------
// Kernel 4: histogram of code usage (LDS-staged).
__global__ __launch_bounds__(256) void hist_kernel(const float* __restrict__ idxf,
                                                   int* __restrict__ ghist) {
    __shared__ int h[K_CODES];
    for (int k = threadIdx.x; k < K_CODES; k += 256) h[k] = 0;
    __syncthreads();
    for (int n = blockIdx.x * 256 + threadIdx.x; n < N_POS; n += gridDim.x * 256)
        atomicAdd(&h[(int)idxf[n]], 1);
    __syncthreads();
    for (int k = threadIdx.x; k < K_CODES; k += 256) {
        int c = h[k];
        if (c) atomicAdd(&ghist[k], c);
    }
}

// ---------------------------------------------------------------------------
// Kernel 5: finalize vq_loss and perplexity. 1 block, 512 threads.
__global__ __launch_bounds__(512) void finalize_kernel(const int* __restrict__ ghist,
                                                       const double* __restrict__ loss,
                                                       float* __restrict__ out) {
    int k = threadIdx.x;
    double p = (double)ghist[k] / (double)N_POS;
    double t = p * log(p + 1e-10);
    for (int off = 32; off; off >>= 1) t += __shfl_down(t, off);
    __shared__ double red[8];
    if ((k & 63) == 0) red[k >> 6] = t;
    __syncthreads();
    if (k == 0) {
        double sum = 0.0;
        for (int i = 0; i < 8; ++i) sum += red[i];
        double perp = exp(-sum);
        double mse  = (*loss) / (double)ZQ_ELEMS;
        out[OUT_LOSS] = (float)(1.25 * mse);   // codebook + 0.25*commit, same MSE
        out[OUT_PERP] = (float)perp;
    }
}

// ---------------------------------------------------------------------------
extern "C" void kernel_launch(void* const* d_in, const int* in_sizes, int n_in,
                              void* d_out, int out_size, void* d_ws, size_t ws_size,
                              hipStream_t stream) {
    const float* z = (const float*)d_in[0];
    const float* e = (const float*)d_in[1];
    float* out = (float*)d_out;
    char* ws = (char*)d_ws;

    double* loss  = (double*)(ws + WS_LOSS);
    int*    ghist = (int*)(ws + WS_HIST);
    float*  e2    = (float*)(ws + WS_E2);
    float*  idxf  = out + OUT_IDXB;

    hipMemsetAsync(d_ws, 0, WS_FIXED, stream);   // zero loss + hist

    e2_kernel   <<<2, 256, 0, stream>>>(e, e2);
    pass1_dist  <<<N_POS / 256, 256, 0, stream>>>(z, e, e2, idxf);
    gather_loss <<<1024, 256, 0, stream>>>(z, e, idxf, out, loss);
    hist_kernel <<<128, 256, 0, stream>>>(idxf, ghist);
    finalize_kernel<<<1, 512, 0, stream>>>(ghist, loss, out);
}

// Round 3
// 1207.638 us; speedup vs baseline: 1.2739x; 1.2739x over previous
//
#include <hip/hip_runtime.h>
#include <math.h>

// Problem constants
#define N_POS     131072          // 8 * 16*32*32 positions
#define DIM       256
#define K_CODES   512
#define S_SPATIAL 16384           // 16*32*32
#define ZQ_ELEMS  33554432        // 8*256*16384
#define OUT_LOSS  33554432
#define OUT_IDXB  33554433        // idx written as float here
#define OUT_PERP  (33554433 + 131072)

// Workspace layout (bytes) — only ~2.1 KB used (safe for any ws_size)
#define WS_LOSS   0               // double
#define WS_HIST   16              // int[512]
#define WS_E2     2064            // float[512]
#define WS_FIXED  2064            // bytes zeroed (loss + hist)

// ---------------------------------------------------------------------------
// Kernel 1: codebook squared norms s_e[k], numpy-pairwise replica.
__global__ __launch_bounds__(256) void e2_kernel(const float* __restrict__ e,
                                                 float* __restrict__ e2) {
    int k = blockIdx.x * 256 + threadIdx.x;
    if (k >= K_CODES) return;
    const float* row = e + (size_t)k * DIM;
    float half[2];
#pragma unroll
    for (int h = 0; h < 2; ++h) {
        const float* base = row + h * 128;
        float r[8];
#pragma unroll
        for (int j = 0; j < 8; ++j) {
            float v = base[j];
            r[j] = __fmul_rn(v, v);
        }
        for (int i = 8; i < 128; i += 8) {
#pragma unroll
            for (int j = 0; j < 8; ++j) {
                float v = base[i + j];
                r[j] = __fadd_rn(r[j], __fmul_rn(v, v));
            }
        }
        half[h] = __fadd_rn(__fadd_rn(__fadd_rn(r[0], r[1]), __fadd_rn(r[2], r[3])),
                            __fadd_rn(__fadd_rn(r[4], r[5]), __fadd_rn(r[6], r[7])));
    }
    e2[k] = __fadd_rn(half[0], half[1]);
}

// ---------------------------------------------------------------------------
// Kernel 2: fp32 distance + argmin, split-K. blockIdx.x = position block,
// blockIdx.y = K chunk (128 codes). Bit-replicates numpy:
//   d[n,k] = fl( fl(s_z[n] + s_e[k]) - fl(2 * G[n,k]) ),
//   G = sequential fp32 FMA over d=0..255. Cross-chunk argmin via u64
//   atomicMin on (dist_bits << 32 | idx): dist > 0 always (~256), so float
//   bits are unsigned-monotonic; low-bits idx => first-index tie rule.
__global__ __launch_bounds__(256) void pass1_dist(const float* __restrict__ z,
                                                  const float* __restrict__ e,
                                                  const float* __restrict__ e2,
                                                  unsigned long long* __restrict__ packed) {
    int n = blockIdx.x * 256 + threadIdx.x;
    int kbase = blockIdx.y * 128;
    int b = n >> 14;
    int s = n & (S_SPATIAL - 1);
    const float* zp = z + (size_t)b * (DIM * S_SPATIAL) + s;

    // s_z: numpy pairwise over fl(z_d^2) — identical bits in every chunk
    float sz;
    {
        float half[2];
#pragma unroll
        for (int h = 0; h < 2; ++h) {
            const float* base = zp + (size_t)(h * 128) * S_SPATIAL;
            float r[8];
#pragma unroll
            for (int j = 0; j < 8; ++j) {
                float v = base[(size_t)j * S_SPATIAL];
                r[j] = __fmul_rn(v, v);
            }
            for (int i = 8; i < 128; i += 8) {
#pragma unroll
                for (int j = 0; j < 8; ++j) {
                    float v = base[(size_t)(i + j) * S_SPATIAL];
                    r[j] = __fadd_rn(r[j], __fmul_rn(v, v));
                }
            }
            half[h] = __fadd_rn(__fadd_rn(__fadd_rn(r[0], r[1]), __fadd_rn(r[2], r[3])),
                                __fadd_rn(__fadd_rn(r[4], r[5]), __fadd_rn(r[6], r[7])));
        }
        sz = __fadd_rn(half[0], half[1]);
    }

    float best = 3.4e38f;
    int bidx = kbase;

    for (int kt = 0; kt < 128; kt += 32) {
        float acc[32];
#pragma unroll
        for (int k = 0; k < 32; ++k) acc[k] = 0.f;
        const float* eb = e + (size_t)(kbase + kt) * DIM;

        for (int d0 = 0; d0 < DIM; d0 += 4) {
            float z0 = zp[(size_t)(d0 + 0) * S_SPATIAL];
            float z1 = zp[(size_t)(d0 + 1) * S_SPATIAL];
            float z2 = zp[(size_t)(d0 + 2) * S_SPATIAL];
            float z3 = zp[(size_t)(d0 + 3) * S_SPATIAL];
#pragma unroll
            for (int k = 0; k < 32; ++k) {
                const float* ek = eb + k * DIM + d0;
                float a = acc[k];
                a = __fmaf_rn(z0, ek[0], a);   // sequential FMA, ascending d
                a = __fmaf_rn(z1, ek[1], a);
                a = __fmaf_rn(z2, ek[2], a);
                a = __fmaf_rn(z3, ek[3], a);
                acc[k] = a;
            }
        }
#pragma unroll
        for (int k = 0; k < 32; ++k) {
            int kk = kbase + kt + k;
            float t1   = __fadd_rn(sz, e2[kk]);
            float dist = __fsub_rn(t1, __fmul_rn(2.0f, acc[k]));
            if (dist < best) { best = dist; bidx = kk; }   // first-index ties
        }
    }

    unsigned long long key =
        ((unsigned long long)__float_as_uint(best) << 32) | (unsigned int)bidx;
    atomicMin(&packed[n], key);
}

// ---------------------------------------------------------------------------
// Kernel 3: unpack packed argmin -> idxf (float), + code-usage histogram.
__global__ __launch_bounds__(256) void unpack_hist(const unsigned long long* __restrict__ packed,
                                                   float* __restrict__ idxf,
                                                   int* __restrict__ ghist) {
    __shared__ int h[K_CODES];
    for (int k = threadIdx.x; k < K_CODES; k += 256) h[k] = 0;
    __syncthreads();
    int n = blockIdx.x * 256 + threadIdx.x;           // grid covers N_POS exactly
    int idx = (int)(unsigned int)(packed[n] & 0xffffffffull);
    idxf[n] = (float)idx;
    atomicAdd(&h[idx], 1);
    __syncthreads();
    for (int k = threadIdx.x; k < K_CODES; k += 256) {
        int c = h[k];
        if (c) atomicAdd(&ghist[k], c);
    }
}

// ---------------------------------------------------------------------------
// Kernel 4: gather z_q = fl(z + fl(e[idx]-z)) + loss accumulation (double).
// Thread = (batch b, sp group of 4, d range of 64). float4 z/out/e traffic;
// idx read once per thread (idxf is only 4B-aligned -> scalar idx loads).
__global__ __launch_bounds__(256) void gather_loss(const float* __restrict__ z,
                                                   const float* __restrict__ e,
                                                   const float* __restrict__ idxf,
                                                   float* __restrict__ out,
                                                   double* __restrict__ loss) {
    int t = blockIdx.x * 256 + threadIdx.x;   // 131072 threads total
    int b   = t >> 14;
    int r   = t & 16383;
    int dg  = r >> 12;                        // 0..3 -> d range [dg*64, dg*64+64)
    int sp  = (r & 4095) << 2;                // sp multiple of 4
    int n0  = (b << 14) + sp;

    int k0 = (int)idxf[n0 + 0];
    int k1 = (int)idxf[n0 + 1];
    int k2 = (int)idxf[n0 + 2];
    int k3 = (int)idxf[n0 + 3];
    const float* e0 = e + (size_t)k0 * DIM;
    const float* e1 = e + (size_t)k1 * DIM;
    const float* e2p = e + (size_t)k2 * DIM;
    const float* e3 = e + (size_t)k3 * DIM;

    const float* zb = z + ((size_t)b * DIM << 14) + sp;
    float* ob = out + ((size_t)b * DIM << 14) + sp;

    double acc = 0.0;
    int dend = dg * 64 + 64;
    for (int d0 = dg * 64; d0 < dend; d0 += 4) {
        float4 ev0 = *(const float4*)(e0 + d0);   // components: dd=0..3 for k0
        float4 ev1 = *(const float4*)(e1 + d0);
        float4 ev2 = *(const float4*)(e2p + d0);
        float4 ev3 = *(const float4*)(e3 + d0);
#pragma unroll
        for (int dd = 0; dd < 4; ++dd) {
            size_t off = ((size_t)(d0 + dd) << 14);
            float4 zv = *(const float4*)(zb + off);
            float ea = (dd == 0) ? ev0.x : (dd == 1) ? ev0.y : (dd == 2) ? ev0.z : ev0.w;
            float eb_ = (dd == 0) ? ev1.x : (dd == 1) ? ev1.y : (dd == 2) ? ev1.z : ev1.w;
            float ec = (dd == 0) ? ev2.x : (dd == 1) ? ev2.y : (dd == 2) ? ev2.z : ev2.w;
            float ed = (dd == 0) ? ev3.x : (dd == 1) ? ev3.y : (dd == 2) ? ev3.z : ev3.w;
            float d0f = __fsub_rn(ea, zv.x);
            float d1f = __fsub_rn(eb_, zv.y);
            float d2f = __fsub_rn(ec, zv.z);
            float d3f = __fsub_rn(ed, zv.w);
            float4 ov;
            ov.x = __fadd_rn(zv.x, d0f);
            ov.y = __fadd_rn(zv.y, d1f);
            ov.z = __fadd_rn(zv.z, d2f);
            ov.w = __fadd_rn(zv.w, d3f);
            *(float4*)(ob + off) = ov;
            acc += (double)d0f * (double)d0f;
            acc += (double)d1f * (double)d1f;
            acc += (double)d2f * (double)d2f;
            acc += (double)d3f * (double)d3f;
        }
    }
    // block reduce (4 waves)
    for (int off = 32; off; off >>= 1) acc += __shfl_down(acc, off);
    __shared__ double red[4];
    if ((threadIdx.x & 63) == 0) red[threadIdx.x >> 6] = acc;
    __syncthreads();
    if (threadIdx.x == 0) {
        double tsum = red[0] + red[1] + red[2] + red[3];
        atomicAdd(loss, tsum);
    }
}

// ---------------------------------------------------------------------------
// Kernel 5: finalize vq_loss and perplexity. 1 block, 512 threads.
__global__ __launch_bounds__(512) void finalize_kernel(const int* __restrict__ ghist,
                                                       const double* __restrict__ loss,
                                                       float* __restrict__ out) {
    int k = threadIdx.x;
    double p = (double)ghist[k] / (double)N_POS;
    double t = p * log(p + 1e-10);
    for (int off = 32; off; off >>= 1) t += __shfl_down(t, off);
    __shared__ double red[8];
    if ((k & 63) == 0) red[k >> 6] = t;
    __syncthreads();
    if (k == 0) {
        double sum = 0.0;
        for (int i = 0; i < 8; ++i) sum += red[i];
        double perp = exp(-sum);
        double mse  = (*loss) / (double)ZQ_ELEMS;
        out[OUT_LOSS] = (float)(1.25 * mse);   // codebook + 0.25*commit, same MSE
        out[OUT_PERP] = (float)perp;
    }
}

// ---------------------------------------------------------------------------
extern "C" void kernel_launch(void* const* d_in, const int* in_sizes, int n_in,
                              void* d_out, int out_size, void* d_ws, size_t ws_size,
                              hipStream_t stream) {
    const float* z = (const float*)d_in[0];
    const float* e = (const float*)d_in[1];
    float* out = (float*)d_out;
    char* ws = (char*)d_ws;

    double* loss  = (double*)(ws + WS_LOSS);
    int*    ghist = (int*)(ws + WS_HIST);
    float*  e2    = (float*)(ws + WS_E2);
    float*  idxf  = out + OUT_IDXB;

    // Packed (dist,idx) scratch lives in the z_q output region (overwritten
    // by gather_loss afterwards) — avoids any assumption about ws_size.
    unsigned long long* packed = (unsigned long long*)d_out;

    hipMemsetAsync(d_ws, 0, WS_FIXED, stream);                 // loss + hist = 0
    hipMemsetAsync(d_out, 0xFF, (size_t)N_POS * 8, stream);    // packed = UINT64_MAX

    e2_kernel   <<<2, 256, 0, stream>>>(e, e2);
    pass1_dist  <<<dim3(N_POS / 256, 4), 256, 0, stream>>>(z, e, e2, packed);
    unpack_hist <<<N_POS / 256, 256, 0, stream>>>(packed, idxf, ghist);
    gather_loss <<<N_POS / 256, 256, 0, stream>>>(z, e, idxf, out, loss);
    finalize_kernel<<<1, 512, 0, stream>>>(ghist, loss, out);
}